// Round 8
// baseline (360.866 us; speedup 1.0000x reference)
//
#include <hip/hip_runtime.h>

#define U_NODES 200000
#define B_ROWS  20000
#define K_S     33
#define F_DIM   256
#define E_DIM   128
#define NBLK    1563            // ceil(U_NODES / 128)

typedef __bf16 bf16x8 __attribute__((ext_vector_type(8)));
typedef float  f32x4  __attribute__((ext_vector_type(4)));
typedef unsigned short ushortx4 __attribute__((ext_vector_type(4)));
typedef unsigned short ushortx8 __attribute__((ext_vector_type(8)));

__device__ __forceinline__ unsigned short f2bf(float f) {
    unsigned int u = __builtin_bit_cast(unsigned int, f);
    u += 0x7fffu + ((u >> 16) & 1u);            // round-to-nearest-even
    return (unsigned short)(u >> 16);
}
__device__ __forceinline__ float bf2f(unsigned short s) {
    return __builtin_bit_cast(float, ((unsigned int)s) << 16);
}
__device__ __forceinline__ bf16x8 pack_bf8(f32x4 a, f32x4 b) {
    ushortx8 r;
    r[0] = f2bf(a[0]); r[1] = f2bf(a[1]); r[2] = f2bf(a[2]); r[3] = f2bf(a[3]);
    r[4] = f2bf(b[0]); r[5] = f2bf(b[1]); r[6] = f2bf(b[2]); r[7] = f2bf(b[3]);
    return __builtin_bit_cast(bf16x8, r);
}

// ---------------------------------------------------------------------------
// One-time prep: Wt[n][k] = bf16(W[k][n]) so B-fragments are contiguous-k.
// ---------------------------------------------------------------------------
__global__ void wprep_kernel(const float* __restrict__ W, unsigned short* __restrict__ Wt) {
    int n = blockIdx.x;      // 128
    int k = threadIdx.x;     // 256
    Wt[n * F_DIM + k] = f2bf(W[(size_t)k * E_DIM + n]);
}

// ---------------------------------------------------------------------------
// MFMA bf16 GEMM: h = bf16(A @ W), fused BN column sum/sumsq.
// v7: FULL-DEPTH register prefetch. All 4 K-chunks of A (32 f32x4/thread)
// issued upfront, before Wt staging; the single __syncthreads vmcnt(0) drain
// is the ONLY memory wait. K-loop = 128 back-to-back MFMAs from registers,
// zero mid-loop vmcnt. Isolates "per-wave pipeline depth" vs "memory service
// ceiling" as gemm's 122-us cause (v1/v3/v4 all ~depth-1, all ~122-130).
// Static reg names pA..pD (rule #20: no runtime-indexed ext_vector arrays).
// Epilogue/stats identical to R2-verified v3.
// ---------------------------------------------------------------------------
__global__ __launch_bounds__(256) void gemm_stats_kernel(
    const float* __restrict__ A, const unsigned short* __restrict__ Wt,
    unsigned short* __restrict__ h, float* __restrict__ partial)
{
    __shared__ __attribute__((aligned(16))) char smem[65536];
    char* Ws = smem;    // [128 n][256 k] bf16, 512 B rows, quad-swizzled

    const int t    = threadIdx.x;
    const int lane = t & 63;
    const int wv   = t >> 6;        // wave 0..3
    const int m    = lane & 15;
    const int qd   = lane >> 4;     // k-quad 0..3
    const int row0 = blockIdx.x * 128;

    int gr0 = row0 + wv * 32 + m;       if (gr0 >= U_NODES) gr0 = U_NODES - 1;
    int gr1 = row0 + wv * 32 + 16 + m;  if (gr1 >= U_NODES) gr1 = U_NODES - 1;
    const float* pa0 = A + (size_t)gr0 * F_DIM + qd * 8;
    const float* pa1 = A + (size_t)gr1 * F_DIM + qd * 8;

#define LOAD_CHUNK(P, c) do {                                                  \
        P[0] = *(const f32x4*)(pa0 + (c) * 64);                                \
        P[1] = *(const f32x4*)(pa0 + (c) * 64 + 4);                            \
        P[2] = *(const f32x4*)(pa0 + (c) * 64 + 32);                           \
        P[3] = *(const f32x4*)(pa0 + (c) * 64 + 36);                           \
        P[4] = *(const f32x4*)(pa1 + (c) * 64);                                \
        P[5] = *(const f32x4*)(pa1 + (c) * 64 + 4);                            \
        P[6] = *(const f32x4*)(pa1 + (c) * 64 + 32);                           \
        P[7] = *(const f32x4*)(pa1 + (c) * 64 + 36);                           \
    } while (0)

#define COMPUTE_CHUNK(P, c) do {                                               \
        bf16x8 a00 = pack_bf8(P[0], P[1]);                                     \
        bf16x8 a01 = pack_bf8(P[2], P[3]);                                     \
        bf16x8 a10 = pack_bf8(P[4], P[5]);                                     \
        bf16x8 a11 = pack_bf8(P[6], P[7]);                                     \
        _Pragma("unroll")                                                      \
        for (int ct = 0; ct < 8; ++ct) {                                       \
            int rb = ct * 16 + m;                                              \
            bf16x8 b0 = *(const bf16x8*)(Ws + rb * 512 +                       \
                            ((((c) * 8 + qd) ^ (rb & 7)) << 4));               \
            acc0[ct] = __builtin_amdgcn_mfma_f32_16x16x32_bf16(a00, b0, acc0[ct], 0, 0, 0); \
            acc1[ct] = __builtin_amdgcn_mfma_f32_16x16x32_bf16(a10, b0, acc1[ct], 0, 0, 0); \
            bf16x8 b1 = *(const bf16x8*)(Ws + rb * 512 +                       \
                            ((((c) * 8 + 4 + qd) ^ (rb & 7)) << 4));           \
            acc0[ct] = __builtin_amdgcn_mfma_f32_16x16x32_bf16(a01, b1, acc0[ct], 0, 0, 0); \
            acc1[ct] = __builtin_amdgcn_mfma_f32_16x16x32_bf16(a11, b1, acc1[ct], 0, 0, 0); \
        }                                                                      \
    } while (0)

    // ---- issue ALL A loads (32 insts, 2 KB/lane in flight) ----
    f32x4 pA[8], pB[8], pC[8], pD[8];
    LOAD_CHUNK(pA, 0);
    LOAD_CHUNK(pB, 1);
    LOAD_CHUNK(pC, 2);
    LOAD_CHUNK(pD, 3);

    // ---- stage all of Wt into LDS (16 insts), quad-swizzled ----
    #pragma unroll
    for (int i = 0; i < 16; ++i) {
        int flat = t + 256 * i;         // 0..4095 ushort8-slots
        int r = flat >> 5, q = flat & 31;
        ushortx8 v = *(const ushortx8*)(Wt + (size_t)r * F_DIM + q * 8);
        *(ushortx8*)(Ws + r * 512 + ((q ^ (r & 7)) << 4)) = v;
    }

    f32x4 acc0[8], acc1[8];
    #pragma unroll
    for (int ct = 0; ct < 8; ++ct) {
        acc0[ct] = (f32x4){0.f, 0.f, 0.f, 0.f};
        acc1[ct] = (f32x4){0.f, 0.f, 0.f, 0.f};
    }

    __syncthreads();        // single memory wait: drains all 48 loads + LDS

    // ---- pure compute: 128 MFMAs, no memory waits ----
    COMPUTE_CHUNK(pA, 0);
    COMPUTE_CHUNK(pB, 1);
    COMPUTE_CHUNK(pC, 2);
    COMPUTE_CHUNK(pD, 3);

#undef LOAD_CHUNK
#undef COMPUTE_CHUNK

    __syncthreads();                    // all waves done reading Ws

    // ---- fused BN stats (mask clamped tail rows) ----
    // D layout (m89-verified): col = lane&15, row = (lane>>4)*4 + reg
    const bool full = (row0 + 128) <= U_NODES;
    float s[8], sq[8];
    #pragma unroll
    for (int ct = 0; ct < 8; ++ct) {
        float ss = 0.f, qq = 0.f;
        #pragma unroll
        for (int v = 0; v < 4; ++v) {
            float x0 = acc0[ct][v];
            float x1 = acc1[ct][v];
            if (full || (row0 + wv * 32 + qd * 4 + v) < U_NODES)      { ss += x0; qq += x0 * x0; }
            if (full || (row0 + wv * 32 + 16 + qd * 4 + v) < U_NODES) { ss += x1; qq += x1 * x1; }
        }
        s[ct] = ss; sq[ct] = qq;
    }
    float* redS = (float*)smem;            // [16][128]
    float* redQ = (float*)(smem + 8192);   // [16][128]
    int rq = wv * 4 + qd;
    #pragma unroll
    for (int ct = 0; ct < 8; ++ct) {
        redS[rq * 128 + ct * 16 + m] = s[ct];
        redQ[rq * 128 + ct * 16 + m] = sq[ct];
    }
    __syncthreads();
    {
        float tot = 0.f;
        if (t < 128) {
            #pragma unroll
            for (int i = 0; i < 16; ++i) tot += redS[i * 128 + t];
        } else {
            #pragma unroll
            for (int i = 0; i < 16; ++i) tot += redQ[i * 128 + (t - 128)];
        }
        partial[(size_t)blockIdx.x * 256 + t] = tot;
    }
    __syncthreads();

    // ---- h store: AGPR-layout -> LDS transpose -> coalesced bf16x8 stores ----
    unsigned short* tb = (unsigned short*)(smem + wv * 8192);   // [32][128] per wave
    #pragma unroll
    for (int ct = 0; ct < 8; ++ct)
        #pragma unroll
        for (int v = 0; v < 4; ++v) {
            tb[(qd * 4 + v) * 128 + ct * 16 + m]        = f2bf(acc0[ct][v]);
            tb[(16 + qd * 4 + v) * 128 + ct * 16 + m]   = f2bf(acc1[ct][v]);
        }
    __syncthreads();
    #pragma unroll
    for (int i = 0; i < 8; ++i) {
        int idx = lane + 64 * i;            // 0..511
        int r = idx >> 4, c8 = (idx & 15) * 8;
        int gr = row0 + wv * 32 + r;
        if (gr < U_NODES)
            *(ushortx8*)(h + (size_t)gr * E_DIM + c8) = *(const ushortx8*)(tb + r * 128 + c8);
    }
}

// ---------------------------------------------------------------------------
// Fold the per-block partials AND finalize BN scale/shift (merged kernels).
// Block c handles column c: sum (cols 0..127 of partial rows) and sumsq
// (cols 128..255) simultaneously; thread 0 writes scale/shift.
// ---------------------------------------------------------------------------
__global__ __launch_bounds__(256) void reduce_finalize_kernel(
    const float* __restrict__ partial,
    const float* __restrict__ gamma, const float* __restrict__ beta,
    float* __restrict__ scale, float* __restrict__ shift)
{
    __shared__ float redS[256], redQ[256];
    const int c = blockIdx.x;       // 0..127
    const int t = threadIdx.x;
    float a = 0.f, b = 0.f;
    for (int j = t; j < NBLK; j += 256) {
        a += partial[(size_t)j * 256 + c];
        b += partial[(size_t)j * 256 + c + 128];
    }
    redS[t] = a; redQ[t] = b;
    __syncthreads();
    #pragma unroll
    for (int s = 128; s > 0; s >>= 1) {
        if (t < s) { redS[t] += redS[t + s]; redQ[t] += redQ[t + s]; }
        __syncthreads();
    }
    if (t == 0) {
        float mu  = redS[0] * (1.f / U_NODES);
        float var = redQ[0] * (1.f / U_NODES) - mu * mu;
        float inv = rsqrtf(var + 1e-5f);
        float sc  = gamma[c] * inv;
        scale[c] = sc;
        shift[c] = beta[c] - sc * mu;
    }
}

// ---------------------------------------------------------------------------
// Gather + BN + tanh + mean over K=33 (R2-VERIFIED version, reverted from
// the R6 hoist which regressed +14 us). bf16 h rows (256 B): 16 threads/row,
// ushort8 (16 B) per lane, 16 rows per 256-thread block, K fully unrolled.
// ---------------------------------------------------------------------------
__global__ __launch_bounds__(256) void gather_kernel(
    const unsigned short* __restrict__ h, const int* __restrict__ sidx_g,
    const float* __restrict__ scale, const float* __restrict__ shift,
    float* __restrict__ out)
{
    __shared__ int sl[16 * K_S];
    const int t  = threadIdx.x;
    const int g  = t & 15;          // col group: cols g*8..g*8+7
    const int r  = t >> 4;          // row within block
    const int b0 = blockIdx.x * 16;
    for (int i = t; i < 16 * K_S; i += 256) sl[i] = sidx_g[(size_t)b0 * K_S + i];
    float scv[8], shv[8];
    *(float4*)&scv[0] = *(const float4*)(scale + g * 8);
    *(float4*)&scv[4] = *(const float4*)(scale + g * 8 + 4);
    *(float4*)&shv[0] = *(const float4*)(shift + g * 8);
    *(float4*)&shv[4] = *(const float4*)(shift + g * 8 + 4);
    __syncthreads();

    float acc[8] = {0.f, 0.f, 0.f, 0.f, 0.f, 0.f, 0.f, 0.f};
    #pragma unroll
    for (int k = 0; k < K_S; ++k) {
        int idx = sl[r * K_S + k];
        ushortx8 v = *(const ushortx8*)(h + (size_t)idx * E_DIM + g * 8);
        #pragma unroll
        for (int j = 0; j < 8; ++j) {
            float x  = bf2f(v[j]) * scv[j] + shv[j];
            float ex = __expf(2.f * x);                       // tanh = 1 - 2/(e^2x+1)
            acc[j] += 1.f - 2.f * __builtin_amdgcn_rcpf(ex + 1.f);
        }
    }
    float* op = out + (size_t)(b0 + r) * E_DIM + g * 8;
    *(float4*)(op)     = make_float4(acc[0] * (1.f / K_S), acc[1] * (1.f / K_S),
                                     acc[2] * (1.f / K_S), acc[3] * (1.f / K_S));
    *(float4*)(op + 4) = make_float4(acc[4] * (1.f / K_S), acc[5] * (1.f / K_S),
                                     acc[6] * (1.f / K_S), acc[7] * (1.f / K_S));
}

// ---------------------------------------------------------------------------
extern "C" void kernel_launch(void* const* d_in, const int* in_sizes, int n_in,
                              void* d_out, int out_size, void* d_ws, size_t ws_size,
                              hipStream_t stream) {
    const float* features = (const float*)d_in[0];
    const float* W        = (const float*)d_in[1];
    // d_in[2] = bias — provably cancels inside BatchNorm; unused.
    const float* gamma    = (const float*)d_in[3];
    const float* beta     = (const float*)d_in[4];
    const int*   sample   = (const int*)d_in[5];
    float* out = (float*)d_out;

    // ws layout: scale[128] shift[128] | partial[NBLK*256] | Wt[128*256 bf16]
    //            | h[U*128 bf16]
    float* scale   = (float*)d_ws;
    float* shift   = scale + 128;
    float* partial = shift + 128;
    unsigned short* Wt = (unsigned short*)(partial + (size_t)NBLK * 256);
    unsigned short* h  = Wt + 128 * 256;

    wprep_kernel<<<128, 256, 0, stream>>>(W, Wt);
    gemm_stats_kernel<<<NBLK, 256, 0, stream>>>(features, Wt, h, partial);
    reduce_finalize_kernel<<<128, 256, 0, stream>>>(partial, gamma, beta, scale, shift);
    gather_kernel<<<B_ROWS / 16, 256, 0, stream>>>(h, sample, scale, shift, out);
}

// Round 9
// 338.414 us; speedup vs baseline: 1.0663x; 1.0663x over previous
//
#include <hip/hip_runtime.h>

#define U_NODES 200000
#define B_ROWS  20000
#define K_S     33
#define F_DIM   256
#define E_DIM   128
#define NBLK    1563            // ceil(U_NODES / 128)

typedef __bf16 bf16x8 __attribute__((ext_vector_type(8)));
typedef float  f32x4  __attribute__((ext_vector_type(4)));
typedef unsigned short ushortx4 __attribute__((ext_vector_type(4)));
typedef unsigned short ushortx8 __attribute__((ext_vector_type(8)));

typedef const __attribute__((address_space(1))) void* gptr_t;
typedef __attribute__((address_space(3))) void* lptr_t;

__device__ __forceinline__ unsigned short f2bf(float f) {
    unsigned int u = __builtin_bit_cast(unsigned int, f);
    u += 0x7fffu + ((u >> 16) & 1u);            // round-to-nearest-even
    return (unsigned short)(u >> 16);
}
__device__ __forceinline__ float bf2f(unsigned short s) {
    return __builtin_bit_cast(float, ((unsigned int)s) << 16);
}
__device__ __forceinline__ bf16x8 pack_bf8(f32x4 a, f32x4 b) {
    ushortx8 r;
    r[0] = f2bf(a[0]); r[1] = f2bf(a[1]); r[2] = f2bf(a[2]); r[3] = f2bf(a[3]);
    r[4] = f2bf(b[0]); r[5] = f2bf(b[1]); r[6] = f2bf(b[2]); r[7] = f2bf(b[3]);
    return __builtin_bit_cast(bf16x8, r);
}

// ---------------------------------------------------------------------------
// One-time prep: Wt[n][k] = bf16(W[k][n]) so B-fragments are contiguous-k.
// ---------------------------------------------------------------------------
__global__ void wprep_kernel(const float* __restrict__ W, unsigned short* __restrict__ Wt) {
    int n = blockIdx.x;      // 128
    int k = threadIdx.x;     // 256
    Wt[n * F_DIM + k] = f2bf(W[(size_t)k * E_DIM + n]);
}

// ---------------------------------------------------------------------------
// MFMA bf16 GEMM: h = bf16(A @ W), fused BN column sum/sumsq.
// v8: ASYNC-DMA staging (global_load_lds). R3-R8 evidence: v1/v3/v4/v7 all
// compile to the same shallow load schedule (~122-125 us, VGPR 108-120 —
// v7's 4-chunk prefetch NEEDS 210+ VGPR, got 108 -> compiler sank the
// loads; m131-m141 lesson). global_load_lds has NO dest VGPR -> compiler
// cannot sink it; true fire-and-forget DMA (m93->m97: +69%).
// m97 2-barrier K-loop, BK=64: stage A[128][64]f32 (8 issues) + Wt[128][64]
// bf16 (4 issues) -> syncthreads (vmcnt0 drain, hidden by 3 blocks/CU
// cross-block overlap) -> 32 MFMA -> syncthreads. LDS 48KB -> 3 blocks/CU.
// Swizzle (rule #21, both-sides): LINEAR LDS dest + pre-swizzled GLOBAL
// source; reads apply the same XOR. A: sl^(row&15) over 16 slots/row
// (conflict-free); W: sl^(row&7) over 8 slots/row (2-way, free per m136).
// Epilogue/stats identical to R2-verified v3.
// ---------------------------------------------------------------------------
__global__ __launch_bounds__(256) void gemm_stats_kernel(
    const float* __restrict__ A, const unsigned short* __restrict__ Wt,
    unsigned short* __restrict__ h, float* __restrict__ partial)
{
    __shared__ __attribute__((aligned(16))) char smem[49152];
    char* As = smem;            // [128 r][16 slot][16B] fp32, swizzled, 32 KB
    char* Ws = smem + 32768;    // [128 n][ 8 slot][16B] bf16, swizzled, 16 KB

    const int t    = threadIdx.x;
    const int lane = t & 63;
    const int wv   = t >> 6;        // wave 0..3
    const int m    = lane & 15;
    const int qd   = lane >> 4;     // k-quad 0..3
    const int row0 = blockIdx.x * 128;
    const int wb   = t & 192;       // wave base (wv*64), wave-uniform

    const int r0 = wv * 32 + m;     // local rows this lane computes
    const int r1 = r0 + 16;

    f32x4 acc0[8], acc1[8];
    #pragma unroll
    for (int ct = 0; ct < 8; ++ct) {
        acc0[ct] = (f32x4){0.f, 0.f, 0.f, 0.f};
        acc1[ct] = (f32x4){0.f, 0.f, 0.f, 0.f};
    }

    for (int kk = 0; kk < F_DIM; kk += 64) {
        // ---- async stage A chunk [128][64] f32: 8 x global_load_lds(16B) ----
        // linear LDS slot S = i*256+t; row=S>>4, sl=S&15; source col group
        // pre-swizzled so READ at slot (c ^ (row&15)) returns col group c.
        #pragma unroll
        for (int i = 0; i < 8; ++i) {
            int S   = i * 256 + t;
            int row = S >> 4, sl = S & 15;
            int gr  = row0 + row; if (gr >= U_NODES) gr = U_NODES - 1;
            const float* gsrc = A + (size_t)gr * F_DIM + kk + ((sl ^ (row & 15)) << 2);
            __builtin_amdgcn_global_load_lds(
                (gptr_t)gsrc, (lptr_t)(As + ((i * 256 + wb) << 4)), 16, 0, 0);
        }
        // ---- async stage W chunk [128][64] bf16: 4 x global_load_lds(16B) ----
        #pragma unroll
        for (int i = 0; i < 4; ++i) {
            int S   = i * 256 + t;
            int row = S >> 3, sl = S & 7;
            const unsigned short* gsrc = Wt + (size_t)row * F_DIM + kk + ((sl ^ (row & 7)) << 3);
            __builtin_amdgcn_global_load_lds(
                (gptr_t)gsrc, (lptr_t)(Ws + ((i * 256 + wb) << 4)), 16, 0, 0);
        }
        __syncthreads();    // vmcnt(0)+lgkmcnt(0) drain -> LDS chunk ready

        // ---- compute: 2 k-halves x (2 A-frags + 8 B-frags, 16 MFMA) ----
        #pragma unroll
        for (int hh = 0; hh < 2; ++hh) {
            f32x4 a0lo = *(const f32x4*)(As + r0 * 256 + (((hh * 8 + qd * 2)     ^ (r0 & 15)) << 4));
            f32x4 a0hi = *(const f32x4*)(As + r0 * 256 + (((hh * 8 + qd * 2 + 1) ^ (r0 & 15)) << 4));
            f32x4 a1lo = *(const f32x4*)(As + r1 * 256 + (((hh * 8 + qd * 2)     ^ (r1 & 15)) << 4));
            f32x4 a1hi = *(const f32x4*)(As + r1 * 256 + (((hh * 8 + qd * 2 + 1) ^ (r1 & 15)) << 4));
            bf16x8 a0 = pack_bf8(a0lo, a0hi);
            bf16x8 a1 = pack_bf8(a1lo, a1hi);
            #pragma unroll
            for (int ct = 0; ct < 8; ++ct) {
                int rb = ct * 16 + m;
                bf16x8 b = *(const bf16x8*)(Ws + rb * 128 + (((hh * 4 + qd) ^ (rb & 7)) << 4));
                acc0[ct] = __builtin_amdgcn_mfma_f32_16x16x32_bf16(a0, b, acc0[ct], 0, 0, 0);
                acc1[ct] = __builtin_amdgcn_mfma_f32_16x16x32_bf16(a1, b, acc1[ct], 0, 0, 0);
            }
        }
        __syncthreads();    // all waves done reading before next-chunk DMA
    }

    // ---- fused BN stats (mask clamped tail rows) ----
    // D layout (m89-verified): col = lane&15, row = (lane>>4)*4 + reg
    const bool full = (row0 + 128) <= U_NODES;
    float s[8], sq[8];
    #pragma unroll
    for (int ct = 0; ct < 8; ++ct) {
        float ss = 0.f, qq = 0.f;
        #pragma unroll
        for (int v = 0; v < 4; ++v) {
            float x0 = acc0[ct][v];
            float x1 = acc1[ct][v];
            if (full || (row0 + wv * 32 + qd * 4 + v) < U_NODES)      { ss += x0; qq += x0 * x0; }
            if (full || (row0 + wv * 32 + 16 + qd * 4 + v) < U_NODES) { ss += x1; qq += x1 * x1; }
        }
        s[ct] = ss; sq[ct] = qq;
    }
    float* redS = (float*)smem;            // [16][128]
    float* redQ = (float*)(smem + 8192);   // [16][128]
    int rq = wv * 4 + qd;
    #pragma unroll
    for (int ct = 0; ct < 8; ++ct) {
        redS[rq * 128 + ct * 16 + m] = s[ct];
        redQ[rq * 128 + ct * 16 + m] = sq[ct];
    }
    __syncthreads();
    {
        float tot = 0.f;
        if (t < 128) {
            #pragma unroll
            for (int i = 0; i < 16; ++i) tot += redS[i * 128 + t];
        } else {
            #pragma unroll
            for (int i = 0; i < 16; ++i) tot += redQ[i * 128 + (t - 128)];
        }
        partial[(size_t)blockIdx.x * 256 + t] = tot;
    }
    __syncthreads();

    // ---- h store: AGPR-layout -> LDS transpose -> coalesced bf16x8 stores ----
    unsigned short* tb = (unsigned short*)(smem + wv * 8192);   // [32][128] per wave
    #pragma unroll
    for (int ct = 0; ct < 8; ++ct)
        #pragma unroll
        for (int v = 0; v < 4; ++v) {
            tb[(qd * 4 + v) * 128 + ct * 16 + m]        = f2bf(acc0[ct][v]);
            tb[(16 + qd * 4 + v) * 128 + ct * 16 + m]   = f2bf(acc1[ct][v]);
        }
    __syncthreads();
    #pragma unroll
    for (int i = 0; i < 8; ++i) {
        int idx = lane + 64 * i;            // 0..511
        int r = idx >> 4, c8 = (idx & 15) * 8;
        int gr = row0 + wv * 32 + r;
        if (gr < U_NODES)
            *(ushortx8*)(h + (size_t)gr * E_DIM + c8) = *(const ushortx8*)(tb + r * 128 + c8);
    }
}

// ---------------------------------------------------------------------------
// Fold the per-block partials AND finalize BN scale/shift (merged kernels).
// ---------------------------------------------------------------------------
__global__ __launch_bounds__(256) void reduce_finalize_kernel(
    const float* __restrict__ partial,
    const float* __restrict__ gamma, const float* __restrict__ beta,
    float* __restrict__ scale, float* __restrict__ shift)
{
    __shared__ float redS[256], redQ[256];
    const int c = blockIdx.x;       // 0..127
    const int t = threadIdx.x;
    float a = 0.f, b = 0.f;
    for (int j = t; j < NBLK; j += 256) {
        a += partial[(size_t)j * 256 + c];
        b += partial[(size_t)j * 256 + c + 128];
    }
    redS[t] = a; redQ[t] = b;
    __syncthreads();
    #pragma unroll
    for (int s = 128; s > 0; s >>= 1) {
        if (t < s) { redS[t] += redS[t + s]; redQ[t] += redQ[t + s]; }
        __syncthreads();
    }
    if (t == 0) {
        float mu  = redS[0] * (1.f / U_NODES);
        float var = redQ[0] * (1.f / U_NODES) - mu * mu;
        float inv = rsqrtf(var + 1e-5f);
        float sc  = gamma[c] * inv;
        scale[c] = sc;
        shift[c] = beta[c] - sc * mu;
    }
}

// ---------------------------------------------------------------------------
// Gather + BN + tanh + mean over K=33 (R2-VERIFIED version).
// ---------------------------------------------------------------------------
__global__ __launch_bounds__(256) void gather_kernel(
    const unsigned short* __restrict__ h, const int* __restrict__ sidx_g,
    const float* __restrict__ scale, const float* __restrict__ shift,
    float* __restrict__ out)
{
    __shared__ int sl[16 * K_S];
    const int t  = threadIdx.x;
    const int g  = t & 15;          // col group: cols g*8..g*8+7
    const int r  = t >> 4;          // row within block
    const int b0 = blockIdx.x * 16;
    for (int i = t; i < 16 * K_S; i += 256) sl[i] = sidx_g[(size_t)b0 * K_S + i];
    float scv[8], shv[8];
    *(float4*)&scv[0] = *(const float4*)(scale + g * 8);
    *(float4*)&scv[4] = *(const float4*)(scale + g * 8 + 4);
    *(float4*)&shv[0] = *(const float4*)(shift + g * 8);
    *(float4*)&shv[4] = *(const float4*)(shift + g * 8 + 4);
    __syncthreads();

    float acc[8] = {0.f, 0.f, 0.f, 0.f, 0.f, 0.f, 0.f, 0.f};
    #pragma unroll
    for (int k = 0; k < K_S; ++k) {
        int idx = sl[r * K_S + k];
        ushortx8 v = *(const ushortx8*)(h + (size_t)idx * E_DIM + g * 8);
        #pragma unroll
        for (int j = 0; j < 8; ++j) {
            float x  = bf2f(v[j]) * scv[j] + shv[j];
            float ex = __expf(2.f * x);                       // tanh = 1 - 2/(e^2x+1)
            acc[j] += 1.f - 2.f * __builtin_amdgcn_rcpf(ex + 1.f);
        }
    }
    float* op = out + (size_t)(b0 + r) * E_DIM + g * 8;
    *(float4*)(op)     = make_float4(acc[0] * (1.f / K_S), acc[1] * (1.f / K_S),
                                     acc[2] * (1.f / K_S), acc[3] * (1.f / K_S));
    *(float4*)(op + 4) = make_float4(acc[4] * (1.f / K_S), acc[5] * (1.f / K_S),
                                     acc[6] * (1.f / K_S), acc[7] * (1.f / K_S));
}

// ---------------------------------------------------------------------------
extern "C" void kernel_launch(void* const* d_in, const int* in_sizes, int n_in,
                              void* d_out, int out_size, void* d_ws, size_t ws_size,
                              hipStream_t stream) {
    const float* features = (const float*)d_in[0];
    const float* W        = (const float*)d_in[1];
    // d_in[2] = bias — provably cancels inside BatchNorm; unused.
    const float* gamma    = (const float*)d_in[3];
    const float* beta     = (const float*)d_in[4];
    const int*   sample   = (const int*)d_in[5];
    float* out = (float*)d_out;

    // ws layout: scale[128] shift[128] | partial[NBLK*256] | Wt[128*256 bf16]
    //            | h[U*128 bf16]
    float* scale   = (float*)d_ws;
    float* shift   = scale + 128;
    float* partial = shift + 128;
    unsigned short* Wt = (unsigned short*)(partial + (size_t)NBLK * 256);
    unsigned short* h  = Wt + 128 * 256;

    wprep_kernel<<<128, 256, 0, stream>>>(W, Wt);
    gemm_stats_kernel<<<NBLK, 256, 0, stream>>>(features, Wt, h, partial);
    reduce_finalize_kernel<<<128, 256, 0, stream>>>(partial, gamma, beta, scale, shift);
    gather_kernel<<<B_ROWS / 16, 256, 0, stream>>>(h, sample, scale, shift, out);
}